// Round 7
// baseline (617.842 us; speedup 1.0000x reference)
//
#include <hip/hip_runtime.h>
#include <math.h>

// ---- problem constants ----
#define TT   512
#define BI   12
#define HH   50
#define BB   4     // batch per block
#define BTOT 2048

// R7: two independent 512-thread blocks per CU (grid 512, BB=4) so one
// block's waves fill the other's barrier drain (R6 was 1 block/CU, 40% of
// the step was barrier stall). 8 waves: wv>>2 = layer, wl = wv&3; wave wl
// owns M-tiles {wl, wl+4, wl+8, wl+12(<13)}. 4-slot merge via per-wave LDS
// scratch (4x ds_write_b128 + 1x ds_read_b128, same-wave RAW, no barrier)
// puts all 4 gates of one (unit,batch-col) in each lane's f4 -> one
// activation bundle per wave (trans count per CU unchanged vs R6).
// B = [x;h] in LDS fragment order [k>>3][n][k&7]; only n-cols 0-3 carry
// real batch; rest are zero-padding (MFMA N-waste, by design).
// Ping-pong parities, 1 barrier/step, layers pipelined by one step (exact).

typedef _Float16 half8 __attribute__((ext_vector_type(8)));
typedef float    f4    __attribute__((ext_vector_type(4)));

__device__ __forceinline__ float sigm_(float v) {
    return __builtin_amdgcn_rcpf(1.f + __expf(-v));
}
__device__ __forceinline__ float tanh_(float v) {
    return 1.f - 2.f * __builtin_amdgcn_rcpf(__expf(2.f * v) + 1.f);
}

__launch_bounds__(512, 4)
__global__ void lstm2_kernel(const float* __restrict__ x,
                             const float* __restrict__ w_ih0, const float* __restrict__ w_hh0,
                             const float* __restrict__ b_ih0, const float* __restrict__ b_hh0,
                             const float* __restrict__ w_ih1, const float* __restrict__ w_hh1,
                             const float* __restrict__ b_ih1, const float* __restrict__ b_hh1,
                             const float* __restrict__ w_out, const float* __restrict__ b_out,
                             float* __restrict__ out)
{
    const int tid   = threadIdx.x;
    const int wv    = tid >> 6;          // 0..7
    const int lane  = tid & 63;
    const int layer = wv >> 2;           // 0 or 1
    const int wl    = wv & 3;            // wave within layer
    const int b0    = blockIdx.x * BB;
    const int ntile = (wl == 0) ? 4 : 3; // tiles wl, wl+4, wl+8 (, 12)

    __shared__ __align__(16) _Float16 B0s[2][64  * 16];
    __shared__ __align__(16) _Float16 B1s[2][128 * 16];
    __shared__ __align__(16) f4 scr[8][64];   // per-wave merge scratch

    // ---- step-invariant A fragments (weights, fragment layout) ----
    // A[m=lane&15][k=q*8+j]; row m -> (u = T*4 + (m>>2), gate = m&3).
    const int m = lane & 15;
    const int q = lane >> 4;
    half8 af[4][4];
    #pragma unroll
    for (int s = 0; s < 4; s++) {
        const int T = wl + 4 * s;
        #pragma unroll
        for (int kb = 0; kb < 4; kb++) {
            #pragma unroll
            for (int j = 0; j < 8; j++) {
                float v = 0.f;
                if (T <= 12 && (layer == 1 || kb < 2)) {
                    const int u  = T * 4 + (m >> 2);
                    const int g  = m & 3;
                    const int kg = kb * 32 + q * 8 + j;
                    if (u < HH) {
                        const int r = g * HH + u;
                        if (layer == 0) {
                            if      (kg < 12)  v = w_ih0[r * BI + kg];
                            else if (kg < 62)  v = w_hh0[r * HH + (kg - 12)];
                            else if (kg == 62) v = b_ih0[r] + b_hh0[r];
                        } else {
                            if      (kg < 50)  v = w_ih1[r * HH + kg];
                            else if (kg < 64)  v = 0.f;
                            else if (kg < 114) v = w_hh1[r * HH + (kg - 64)];
                            else if (kg == 114) v = b_ih1[r] + b_hh1[r];
                        }
                    }
                }
                af[s][kb][j] = (_Float16)v;
            }
        }
    }

    // ---- init LDS ----
    for (int i = tid; i < 2 * 64 * 16;  i += 512) (&B0s[0][0])[i] = (_Float16)0.f;
    for (int i = tid; i < 2 * 128 * 16; i += 512) (&B1s[0][0])[i] = (_Float16)0.f;
    __syncthreads();
    if (tid < 16) {                       // bias (ones) rows, both parities
        B0s[0][7  * 128 + tid * 8 + 6] = (_Float16)1.f;
        B0s[1][7  * 128 + tid * 8 + 6] = (_Float16)1.f;
        B1s[0][14 * 128 + tid * 8 + 2] = (_Float16)1.f;
        B1s[1][14 * 128 + tid * 8 + 2] = (_Float16)1.f;
    }
    const int xb = tid / 12, xi = tid - xb * 12;           // tid<48 roles
    const int xoff = (xi >> 3) * 128 + xb * 8 + (xi & 7);
    const size_t xbase = ((size_t)(b0 + xb) * TT) * BI + xi;
    if (tid < 48)                          // x[0] -> parity 0
        B0s[0][xoff] = (_Float16)x[xbase];
    __syncthreads();

    // ---- merged update role: lane owns (u_m, bcol) via 4-slot merge ----
    const int n16  = lane & 15;
    const int slot = n16 >> 2;            // which of this wave's 4 tiles
    const int bcol = n16 & 3;             // batch column 0..3
    const int Ts   = wl + 4 * slot;
    const int u_m  = Ts * 4 + q;
    const bool wvalid = (Ts <= 12) && (u_m < HH);
    float cm = 0.f;

    // ---- per-parity pointers ----
    const _Float16* rd0 = (layer ? &B1s[0][0] : &B0s[0][0]) + lane * 8;
    const _Float16* rd1 = (layer ? &B1s[1][0] : &B0s[1][0]) + lane * 8;
    const int k0 = 12 + u_m;              // h0 row in B0 (layer0)
    const int k1 = 64 + u_m;              // h1 row in B1 (layer1)
    const int offA = layer ? ((k1 >> 3) * 128 + bcol * 8 + (k1 & 7))
                           : ((k0 >> 3) * 128 + bcol * 8 + (k0 & 7));
    const int offB = (u_m >> 3) * 128 + bcol * 8 + (u_m & 7); // h0 row in B1
    _Float16* wA0 = (layer ? &B1s[0][0] : &B0s[0][0]) + offA;
    _Float16* wA1 = (layer ? &B1s[1][0] : &B0s[1][0]) + offA;
    _Float16* wB0 = &B1s[0][0] + offB;
    _Float16* wB1 = &B1s[1][0] + offB;
    _Float16* xd0 = &B0s[0][0] + xoff;
    _Float16* xd1 = &B0s[1][0] + xoff;
    f4* scw = &scr[wv][q * 4 + n16];      // write slot s at + s*16 (n16<4)
    const f4* scrd = &scr[wv][slot * 16 + q * 4 + bcol];

    for (int t = 0; t <= TT; t++) {
        const int p = t & 1;

        // prefetch x[t+1] (independent of recurrence)
        float xpre = 0.f;
        const bool do_x = (tid < 48) && (t + 1 < TT);
        if (do_x) xpre = x[xbase + (size_t)(t + 1) * BI];

        const bool active = layer ? (t >= 1) : (t < TT);
        if (active) {
            f4 acc[4];
            #pragma unroll
            for (int s = 0; s < 4; s++) acc[s] = (f4){0.f, 0.f, 0.f, 0.f};
            const _Float16* Bp = p ? rd1 : rd0;
            if (layer == 0) {
                #pragma unroll
                for (int kb = 0; kb < 2; kb++) {
                    const half8 bf = *(const half8*)(Bp + kb * 512);
                    #pragma unroll
                    for (int s = 0; s < 4; s++)
                        if (s < ntile)
                            acc[s] = __builtin_amdgcn_mfma_f32_16x16x32_f16(af[s][kb], bf, acc[s], 0, 0, 0);
                }
            } else {
                #pragma unroll
                for (int kb = 0; kb < 4; kb++) {
                    const half8 bf = *(const half8*)(Bp + kb * 512);
                    #pragma unroll
                    for (int s = 0; s < 4; s++)
                        if (s < ntile)
                            acc[s] = __builtin_amdgcn_mfma_f32_16x16x32_f16(af[s][kb], bf, acc[s], 0, 0, 0);
                }
            }
            // ---- 4-slot merge via per-wave LDS scratch (no barrier) ----
            if (n16 < 4) {
                #pragma unroll
                for (int s = 0; s < 4; s++)
                    if (s < ntile) scw[s * 16] = acc[s];
            }
            const f4 am = *scrd;
            const float iv = sigm_(am[0]);
            const float fv = sigm_(am[1]);
            const float gv = tanh_(am[2]);
            const float ov = sigm_(am[3]);
            cm = fv * cm + iv * gv;
            const float h = ov * tanh_(cm);
            if (wvalid) {
                const _Float16 hh = (_Float16)h;
                *(p ? wA0 : wA1) = hh;            // write parity = 1-p
                if (layer == 0) *(p ? wB0 : wB1) = hh;
            }
        }
        if (do_x) *(p ? xd0 : xd1) = (_Float16)xpre;
        __syncthreads();
    }

    // ---- epilogue: sigmoid(h1[TT-1] . w_out + b_out); h1[TT-1] in parity 1 ----
    if (tid < BB) {
        float s = b_out[0];
        #pragma unroll
        for (int u = 0; u < HH; u++) {
            const int kk = 64 + u;
            s += w_out[u] * (float)B1s[1][(kk >> 3) * 128 + tid * 8 + (kk & 7)];
        }
        out[b0 + tid] = sigm_(s);
    }
}

extern "C" void kernel_launch(void* const* d_in, const int* in_sizes, int n_in,
                              void* d_out, int out_size, void* d_ws, size_t ws_size,
                              hipStream_t stream) {
    const float* x     = (const float*)d_in[0];
    const float* w_ih0 = (const float*)d_in[1];
    const float* w_hh0 = (const float*)d_in[2];
    const float* b_ih0 = (const float*)d_in[3];
    const float* b_hh0 = (const float*)d_in[4];
    const float* w_ih1 = (const float*)d_in[5];
    const float* w_hh1 = (const float*)d_in[6];
    const float* b_ih1 = (const float*)d_in[7];
    const float* b_hh1 = (const float*)d_in[8];
    const float* w_out = (const float*)d_in[9];
    const float* b_out = (const float*)d_in[10];
    float* out = (float*)d_out;

    dim3 grid(BTOT / BB);   // 512 blocks -> 2 per CU (independent barriers)
    dim3 block(512);        // 8 waves: 4 layer-0 + 4 layer-1
    lstm2_kernel<<<grid, block, 0, stream>>>(x, w_ih0, w_hh0, b_ih0, b_hh0,
                                             w_ih1, w_hh1, b_ih1, b_hh1,
                                             w_out, b_out, out);
}

// Round 8
// 414.672 us; speedup vs baseline: 1.4900x; 1.4900x over previous
//
#include <hip/hip_runtime.h>
#include <math.h>

// ---- problem constants ----
#define TT   512
#define BI   12
#define HH   50
#define BB   8     // batch per block
#define BTOT 2048

// R8 = R6 structure (the 418 us kernel: 1024 thr, BB=8, grid 256, 1 barrier
// per step) with the slot-merge latency removed:
//  - R6's __shfl_xor(acc1,8) + select (4x ds_bpermute ~120cyc + 4 cndmask)
//    is replaced by v_mov_dpp row_ror:8 with bank_mask=0xC: one 2-cyc VALU
//    instr per component merges acc0 (lanes n16<8) with acc1 from lane^8
//    (lanes n16>=8). No LDS pipe, no latency on the trans critical path.
//  - sigmoid/tanh use v_exp_f32 directly with folded scale:
//    sigm(v) = rcp(1+exp2(-1.4427*v)), tanh(v) = 1-2*rcp(1+exp2(2.8854*v)).
// Layout (verified R5/R6): row r = u*4+gate -> each lane's f4 acc holds all
// 4 gates of one (unit,batch); cell update fully in-register. B = [x;h] in
// LDS fragment order [k>>3][n][k&7]; ping-pong parities; layers pipelined
// by one step (exact): iter t: l0 -> h0[t], l1 -> h1[t-1], t = 0..TT.

typedef _Float16 half8 __attribute__((ext_vector_type(8)));
typedef float    f4    __attribute__((ext_vector_type(4)));

#define LOG2E  1.4426950408889634f

__device__ __forceinline__ float sigm_(float v) {
    return __builtin_amdgcn_rcpf(1.f + __builtin_amdgcn_exp2f(v * (-LOG2E)));
}
__device__ __forceinline__ float tanh_(float v) {
    return 1.f - 2.f * __builtin_amdgcn_rcpf(1.f + __builtin_amdgcn_exp2f(v * (2.f * LOG2E)));
}
// merge: lanes with (lane&15)<8 keep a0; lanes with (lane&15)>=8 take a1
// from lane^8 (DPP row_ror:8 = 0x128; banks 2,3 only = bank_mask 0xC).
__device__ __forceinline__ float dppmerge_(float a0, float a1) {
    int r = __builtin_amdgcn_update_dpp(__builtin_bit_cast(int, a0),
                                        __builtin_bit_cast(int, a1),
                                        0x128, 0xF, 0xC, false);
    return __builtin_bit_cast(float, r);
}

__launch_bounds__(1024)
__global__ void lstm2_kernel(const float* __restrict__ x,
                             const float* __restrict__ w_ih0, const float* __restrict__ w_hh0,
                             const float* __restrict__ b_ih0, const float* __restrict__ b_hh0,
                             const float* __restrict__ w_ih1, const float* __restrict__ w_hh1,
                             const float* __restrict__ b_ih1, const float* __restrict__ b_hh1,
                             const float* __restrict__ w_out, const float* __restrict__ b_out,
                             float* __restrict__ out)
{
    const int tid   = threadIdx.x;
    const int wv    = tid >> 6;          // 0..15
    const int lane  = tid & 63;
    const int layer = wv >> 3;           // 0 or 1
    const int w8    = wv & 7;
    const int b0    = blockIdx.x * BB;
    // 13 M-tiles per layer over 8 waves: waves 0-4 take 2, waves 5-7 take 1.
    const int t0     = (w8 < 5) ? 2 * w8 : (5 + w8);
    const int ntiles = (w8 < 5) ? 2 : 1;

    __shared__ __align__(16) _Float16 B0s[2][64  * 16];
    __shared__ __align__(16) _Float16 B1s[2][128 * 16];

    // ---- step-invariant A fragments (weights, fragment layout) ----
    const int m = lane & 15;
    const int q = lane >> 4;
    half8 af[2][4];
    #pragma unroll
    for (int s = 0; s < 2; s++) {
        #pragma unroll
        for (int kb = 0; kb < 4; kb++) {
            #pragma unroll
            for (int j = 0; j < 8; j++) {
                float v = 0.f;
                if (s < ntiles && (layer == 1 || kb < 2)) {
                    const int T  = t0 + s;
                    const int u  = T * 4 + (m >> 2);
                    const int g  = m & 3;
                    const int kg = kb * 32 + q * 8 + j;
                    if (u < HH) {
                        const int r = g * HH + u;
                        if (layer == 0) {
                            if      (kg < 12)  v = w_ih0[r * BI + kg];
                            else if (kg < 62)  v = w_hh0[r * HH + (kg - 12)];
                            else if (kg == 62) v = b_ih0[r] + b_hh0[r];
                        } else {
                            if      (kg < 50)  v = w_ih1[r * HH + kg];
                            else if (kg < 64)  v = 0.f;
                            else if (kg < 114) v = w_hh1[r * HH + (kg - 64)];
                            else if (kg == 114) v = b_ih1[r] + b_hh1[r];
                        }
                    }
                }
                af[s][kb][j] = (_Float16)v;
            }
        }
    }

    // ---- init LDS ----
    for (int i = tid; i < 2 * 64 * 16;  i += 1024) (&B0s[0][0])[i] = (_Float16)0.f;
    for (int i = tid; i < 2 * 128 * 16; i += 1024) (&B1s[0][0])[i] = (_Float16)0.f;
    __syncthreads();
    if (tid < 16) {                       // bias (ones) rows, both parities
        B0s[0][7  * 128 + tid * 8 + 6] = (_Float16)1.f;
        B0s[1][7  * 128 + tid * 8 + 6] = (_Float16)1.f;
        B1s[0][14 * 128 + tid * 8 + 2] = (_Float16)1.f;
        B1s[1][14 * 128 + tid * 8 + 2] = (_Float16)1.f;
    }
    const int xb = tid / 12, xi = tid - xb * 12;           // loop-invariant
    const int xoff = (xi >> 3) * 128 + xb * 8 + (xi & 7);
    if (tid < 96)                          // x[0] -> parity 0
        B0s[0][xoff] = (_Float16)x[((size_t)(b0 + xb) * TT + 0) * BI + xi];
    __syncthreads();

    // ---- merged update role: lane owns (u_m, bcol) ----
    const int n16  = lane & 15;
    const int slot = n16 >> 3;            // 0: own acc0; 1: partner's acc1
    const int bcol = n16 & 7;
    const int u_m  = (t0 + slot) * 4 + q;
    const bool wvalid = (u_m < HH) && (slot == 0 || ntiles == 2);
    float cm = 0.f;                        // cell state for (u_m, bcol)

    // ---- per-parity pointers (precomputed; 1 select per use) ----
    const _Float16* rd0 = (layer ? &B1s[0][0] : &B0s[0][0]) + lane * 8;
    const _Float16* rd1 = (layer ? &B1s[1][0] : &B0s[1][0]) + lane * 8;
    const int k0 = 12 + u_m;              // h0 row in B0
    const int k1 = 64 + u_m;              // h1 row in B1
    const int offA = layer ? ((k1 >> 3) * 128 + bcol * 8 + (k1 & 7))
                           : ((k0 >> 3) * 128 + bcol * 8 + (k0 & 7));
    const int offB = (u_m >> 3) * 128 + bcol * 8 + (u_m & 7);   // h0 row in B1 (layer0)
    _Float16* wA0 = (layer ? &B1s[0][0] : &B0s[0][0]) + offA;   // parity-0 dest
    _Float16* wA1 = (layer ? &B1s[1][0] : &B0s[1][0]) + offA;
    _Float16* wB0 = &B1s[0][0] + offB;
    _Float16* wB1 = &B1s[1][0] + offB;
    _Float16* xd0 = &B0s[0][0] + xoff;
    _Float16* xd1 = &B0s[1][0] + xoff;

    for (int t = 0; t <= TT; t++) {
        const int p = t & 1;

        // prefetch x[t+1] (independent of recurrence)
        float xpre = 0.f;
        const bool do_x = (tid < 96) && (t + 1 < TT);
        if (do_x) xpre = x[((size_t)(b0 + xb) * TT + (t + 1)) * BI + xi];

        const bool active = layer ? (t >= 1) : (t < TT);
        if (active) {
            f4 acc0 = {0.f, 0.f, 0.f, 0.f};
            f4 acc1 = {0.f, 0.f, 0.f, 0.f};
            const _Float16* Bp = p ? rd1 : rd0;
            if (layer == 0) {
                #pragma unroll
                for (int kb = 0; kb < 2; kb++) {
                    const half8 bf = *(const half8*)(Bp + kb * 512);
                    acc0 = __builtin_amdgcn_mfma_f32_16x16x32_f16(af[0][kb], bf, acc0, 0, 0, 0);
                    if (ntiles > 1)
                        acc1 = __builtin_amdgcn_mfma_f32_16x16x32_f16(af[1][kb], bf, acc1, 0, 0, 0);
                }
            } else {
                #pragma unroll
                for (int kb = 0; kb < 4; kb++) {
                    const half8 bf = *(const half8*)(Bp + kb * 512);
                    acc0 = __builtin_amdgcn_mfma_f32_16x16x32_f16(af[0][kb], bf, acc0, 0, 0, 0);
                    if (ntiles > 1)
                        acc1 = __builtin_amdgcn_mfma_f32_16x16x32_f16(af[1][kb], bf, acc1, 0, 0, 0);
                }
            }
            // ---- slot merge: one DPP instr per component, no LDS ----
            f4 am;
            #pragma unroll
            for (int i = 0; i < 4; i++) am[i] = dppmerge_(acc0[i], acc1[i]);

            const float iv = sigm_(am[0]);
            const float fv = sigm_(am[1]);
            const float gv = tanh_(am[2]);
            const float ov = sigm_(am[3]);
            cm = fv * cm + iv * gv;
            const float h = ov * tanh_(cm);
            if (wvalid) {
                const _Float16 hh = (_Float16)h;
                *(p ? wA0 : wA1) = hh;           // write parity = 1-p
                if (layer == 0) *(p ? wB0 : wB1) = hh;
            }
        }
        if (do_x) *(p ? xd0 : xd1) = (_Float16)xpre;
        __syncthreads();
    }

    // ---- epilogue: sigmoid(h1[TT-1] . w_out + b_out); h1[TT-1] in parity 1 ----
    if (tid < BB) {
        float s = b_out[0];
        #pragma unroll
        for (int u = 0; u < HH; u++) {
            const int kk = 64 + u;
            s += w_out[u] * (float)B1s[1][(kk >> 3) * 128 + tid * 8 + (kk & 7)];
        }
        out[b0 + tid] = sigm_(s);
    }
}

extern "C" void kernel_launch(void* const* d_in, const int* in_sizes, int n_in,
                              void* d_out, int out_size, void* d_ws, size_t ws_size,
                              hipStream_t stream) {
    const float* x     = (const float*)d_in[0];
    const float* w_ih0 = (const float*)d_in[1];
    const float* w_hh0 = (const float*)d_in[2];
    const float* b_ih0 = (const float*)d_in[3];
    const float* b_hh0 = (const float*)d_in[4];
    const float* w_ih1 = (const float*)d_in[5];
    const float* w_hh1 = (const float*)d_in[6];
    const float* b_ih1 = (const float*)d_in[7];
    const float* b_hh1 = (const float*)d_in[8];
    const float* w_out = (const float*)d_in[9];
    const float* b_out = (const float*)d_in[10];
    float* out = (float*)d_out;

    dim3 grid(BTOT / BB);   // 256 blocks -> 1 per CU
    dim3 block(1024);       // 16 waves: 8 layer-0 + 8 layer-1
    lstm2_kernel<<<grid, block, 0, stream>>>(x, w_ih0, w_hh0, b_ih0, b_hh0,
                                             w_ih1, w_hh1, b_ih1, b_hh1,
                                             w_out, b_out, out);
}

// Round 9
// 397.420 us; speedup vs baseline: 1.5546x; 1.0434x over previous
//
#include <hip/hip_runtime.h>

// ---- problem constants ----
#define TT   512
#define BI   12
#define HH   50
#define BB   8     // batch per block
#define BTOT 2048
#define LOG2E 1.4426950408889634f

// R9 = R8 (414 us: MFMA fp16, DPP slot-merge, exp2 activations) with the
// t-loop unrolled by 2 at compile-time parity:
//  - peel t=0,1 and t=510,511,512; main loop = 254 x [P0 body; P1 body]
//  - all per-parity pointer selects (4 cndmask-chains), `active` layer
//    checks, and the per-step x-address mul are gone; x advances by a
//    pointer increment.
// Layout (verified R5-R8): row r = u*4+gate -> each lane's f4 acc holds all
// 4 gates of one (unit,batch); cell update fully in-register. B = [x;h] in
// LDS fragment order [k>>3][n][k&7]; ping-pong parities; one barrier/step;
// layers software-pipelined by one step (exact): t: l0->h0[t], l1->h1[t-1].
// Trans-bundle optimality: bundles/CU-step = (units x batch)/64 requires
// tiles/wave x 4 x BB = 64 -> the 16-wave / BB=8 / 2-tile config is the
// unique optimum (R7's 2-block variant doubled trans and regressed).

typedef _Float16 half8 __attribute__((ext_vector_type(8)));
typedef float    f4    __attribute__((ext_vector_type(4)));

__device__ __forceinline__ float sigm_(float v) {
    return __builtin_amdgcn_rcpf(1.f + __builtin_amdgcn_exp2f(v * (-LOG2E)));
}
__device__ __forceinline__ float tanh_(float v) {
    return 1.f - 2.f * __builtin_amdgcn_rcpf(1.f + __builtin_amdgcn_exp2f(v * (2.f * LOG2E)));
}
// lanes with (lane&15)<8 keep a0; lanes with (lane&15)>=8 take a1 from
// lane^8 (DPP row_ror:8 = 0x128, banks 2,3 -> bank_mask 0xC). One VALU op.
__device__ __forceinline__ float dppmerge_(float a0, float a1) {
    int r = __builtin_amdgcn_update_dpp(__builtin_bit_cast(int, a0),
                                        __builtin_bit_cast(int, a1),
                                        0x128, 0xF, 0xC, false);
    return __builtin_bit_cast(float, r);
}

__launch_bounds__(1024)
__global__ void lstm2_kernel(const float* __restrict__ x,
                             const float* __restrict__ w_ih0, const float* __restrict__ w_hh0,
                             const float* __restrict__ b_ih0, const float* __restrict__ b_hh0,
                             const float* __restrict__ w_ih1, const float* __restrict__ w_hh1,
                             const float* __restrict__ b_ih1, const float* __restrict__ b_hh1,
                             const float* __restrict__ w_out, const float* __restrict__ b_out,
                             float* __restrict__ out)
{
    const int tid   = threadIdx.x;
    const int wv    = tid >> 6;          // 0..15
    const int lane  = tid & 63;
    const int layer = wv >> 3;           // 0 or 1
    const int w8    = wv & 7;
    const int b0    = blockIdx.x * BB;
    // 13 M-tiles per layer over 8 waves: waves 0-4 take 2, waves 5-7 take 1.
    const int t0     = (w8 < 5) ? 2 * w8 : (5 + w8);
    const int ntiles = (w8 < 5) ? 2 : 1;

    __shared__ __align__(16) _Float16 B0s[2][64  * 16];
    __shared__ __align__(16) _Float16 B1s[2][128 * 16];

    // ---- step-invariant A fragments (weights, fragment layout) ----
    const int m = lane & 15;
    const int q = lane >> 4;
    half8 af[2][4];
    #pragma unroll
    for (int s = 0; s < 2; s++) {
        #pragma unroll
        for (int kb = 0; kb < 4; kb++) {
            #pragma unroll
            for (int j = 0; j < 8; j++) {
                float v = 0.f;
                if (s < ntiles && (layer == 1 || kb < 2)) {
                    const int T  = t0 + s;
                    const int u  = T * 4 + (m >> 2);
                    const int g  = m & 3;
                    const int kg = kb * 32 + q * 8 + j;
                    if (u < HH) {
                        const int r = g * HH + u;
                        if (layer == 0) {
                            if      (kg < 12)  v = w_ih0[r * BI + kg];
                            else if (kg < 62)  v = w_hh0[r * HH + (kg - 12)];
                            else if (kg == 62) v = b_ih0[r] + b_hh0[r];
                        } else {
                            if      (kg < 50)  v = w_ih1[r * HH + kg];
                            else if (kg < 64)  v = 0.f;
                            else if (kg < 114) v = w_hh1[r * HH + (kg - 64)];
                            else if (kg == 114) v = b_ih1[r] + b_hh1[r];
                        }
                    }
                }
                af[s][kb][j] = (_Float16)v;
            }
        }
    }

    // ---- init LDS ----
    for (int i = tid; i < 2 * 64 * 16;  i += 1024) (&B0s[0][0])[i] = (_Float16)0.f;
    for (int i = tid; i < 2 * 128 * 16; i += 1024) (&B1s[0][0])[i] = (_Float16)0.f;
    __syncthreads();
    if (tid < 16) {                       // bias (ones) rows, both parities
        B0s[0][7  * 128 + tid * 8 + 6] = (_Float16)1.f;
        B0s[1][7  * 128 + tid * 8 + 6] = (_Float16)1.f;
        B1s[0][14 * 128 + tid * 8 + 2] = (_Float16)1.f;
        B1s[1][14 * 128 + tid * 8 + 2] = (_Float16)1.f;
    }
    const int xb = tid / 12, xi = tid - xb * 12;           // loop-invariant
    const int xoff = (xi >> 3) * 128 + xb * 8 + (xi & 7);
    const size_t xbase = ((size_t)(b0 + xb) * TT) * BI + xi;
    if (tid < 96)                          // x[0] -> parity 0
        B0s[0][xoff] = (_Float16)x[xbase];
    __syncthreads();

    // ---- merged update role: lane owns (u_m, bcol) ----
    const int n16  = lane & 15;
    const int slot = n16 >> 3;            // 0: own acc0; 1: partner's acc1
    const int bcol = n16 & 7;
    const int u_m  = (t0 + slot) * 4 + q;
    const bool wvalid = (u_m < HH) && (slot == 0 || ntiles == 2);
    float cm = 0.f;                        // cell state for (u_m, bcol)

    // ---- per-parity pointers (constant-indexed -> folded at compile time) ----
    const _Float16* rdA[2] = { (layer ? &B1s[0][0] : &B0s[0][0]) + lane * 8,
                               (layer ? &B1s[1][0] : &B0s[1][0]) + lane * 8 };
    const int k0 = 12 + u_m;              // h0 row in B0
    const int k1 = 64 + u_m;              // h1 row in B1
    const int offA = layer ? ((k1 >> 3) * 128 + bcol * 8 + (k1 & 7))
                           : ((k0 >> 3) * 128 + bcol * 8 + (k0 & 7));
    const int offB = (u_m >> 3) * 128 + bcol * 8 + (u_m & 7);   // h0 row in B1
    _Float16* wAp[2] = { (layer ? &B1s[0][0] : &B0s[0][0]) + offA,
                         (layer ? &B1s[1][0] : &B0s[1][0]) + offA };
    _Float16* wBp[2] = { &B1s[0][0] + offB, &B1s[1][0] + offB };
    _Float16* xdp[2] = { &B0s[0][0] + xoff, &B0s[1][0] + xoff };

    const float* xq = x + xbase + BI;     // x[t+1] stream (valid lanes tid<96)

// One timestep at compile-time parity P. DOL0/DOL1: layer activity
// (peel boundaries). DOX: prefetch x[t+1] into parity 1-P.
#define STEP(P, DOL0, DOL1, DOX)                                              \
  {                                                                           \
    float xpre = 0.f;                                                         \
    if ((DOX) && tid < 96) xpre = *xq;                                        \
    if ((layer == 0) ? (DOL0) : (DOL1)) {                                     \
      f4 acc0 = {0.f, 0.f, 0.f, 0.f}, acc1 = {0.f, 0.f, 0.f, 0.f};            \
      const _Float16* Bp = rdA[P];                                            \
      if (layer == 0) {                                                       \
        _Pragma("unroll")                                                     \
        for (int kb = 0; kb < 2; kb++) {                                      \
          const half8 bf = *(const half8*)(Bp + kb * 512);                    \
          acc0 = __builtin_amdgcn_mfma_f32_16x16x32_f16(af[0][kb], bf, acc0, 0, 0, 0); \
          if (ntiles > 1)                                                     \
            acc1 = __builtin_amdgcn_mfma_f32_16x16x32_f16(af[1][kb], bf, acc1, 0, 0, 0); \
        }                                                                     \
      } else {                                                                \
        _Pragma("unroll")                                                     \
        for (int kb = 0; kb < 4; kb++) {                                      \
          const half8 bf = *(const half8*)(Bp + kb * 512);                    \
          acc0 = __builtin_amdgcn_mfma_f32_16x16x32_f16(af[0][kb], bf, acc0, 0, 0, 0); \
          if (ntiles > 1)                                                     \
            acc1 = __builtin_amdgcn_mfma_f32_16x16x32_f16(af[1][kb], bf, acc1, 0, 0, 0); \
        }                                                                     \
      }                                                                       \
      f4 am;                                                                  \
      _Pragma("unroll")                                                       \
      for (int i = 0; i < 4; i++) am[i] = dppmerge_(acc0[i], acc1[i]);        \
      const float iv = sigm_(am[0]);                                          \
      const float fv = sigm_(am[1]);                                          \
      const float gv = tanh_(am[2]);                                          \
      const float ov = sigm_(am[3]);                                          \
      cm = fv * cm + iv * gv;                                                 \
      const float h = ov * tanh_(cm);                                         \
      if (wvalid) {                                                           \
        const _Float16 hh = (_Float16)h;                                      \
        *wAp[1 - (P)] = hh;                                                   \
        if (layer == 0) *wBp[1 - (P)] = hh;                                   \
      }                                                                       \
    }                                                                         \
    if ((DOX) && tid < 96) *xdp[1 - (P)] = (_Float16)xpre;                    \
    if (DOX) xq += BI;                                                        \
    __syncthreads();                                                          \
  }

    STEP(0, 1, 0, 1)                      // t = 0   (l0 only)
    STEP(1, 1, 1, 1)                      // t = 1
    #pragma unroll 1
    for (int it = 0; it < 254; ++it) {    // t = 2 .. 509
        STEP(0, 1, 1, 1)
        STEP(1, 1, 1, 1)
    }
    STEP(0, 1, 1, 1)                      // t = 510 (prefetch x[511])
    STEP(1, 1, 1, 0)                      // t = 511 (no prefetch)
    STEP(0, 0, 1, 0)                      // t = 512 (l1 only)
#undef STEP

    // ---- epilogue: sigmoid(h1[TT-1] . w_out + b_out); h1[TT-1] in parity 1 ----
    if (tid < BB) {
        float s = b_out[0];
        #pragma unroll
        for (int u = 0; u < HH; u++) {
            const int kk = 64 + u;
            s += w_out[u] * (float)B1s[1][(kk >> 3) * 128 + tid * 8 + (kk & 7)];
        }
        out[b0 + tid] = sigm_(s);
    }
}

extern "C" void kernel_launch(void* const* d_in, const int* in_sizes, int n_in,
                              void* d_out, int out_size, void* d_ws, size_t ws_size,
                              hipStream_t stream) {
    const float* x     = (const float*)d_in[0];
    const float* w_ih0 = (const float*)d_in[1];
    const float* w_hh0 = (const float*)d_in[2];
    const float* b_ih0 = (const float*)d_in[3];
    const float* b_hh0 = (const float*)d_in[4];
    const float* w_ih1 = (const float*)d_in[5];
    const float* w_hh1 = (const float*)d_in[6];
    const float* b_ih1 = (const float*)d_in[7];
    const float* b_hh1 = (const float*)d_in[8];
    const float* w_out = (const float*)d_in[9];
    const float* b_out = (const float*)d_in[10];
    float* out = (float*)d_out;

    dim3 grid(BTOT / BB);   // 256 blocks -> 1 per CU
    dim3 block(1024);       // 16 waves: 8 layer-0 + 8 layer-1
    lstm2_kernel<<<grid, block, 0, stream>>>(x, w_ih0, w_hh0, b_ih0, b_hh0,
                                             w_ih1, w_hh1, b_ih1, b_hh1,
                                             w_out, b_out, out);
}